// Round 2
// baseline (6332.986 us; speedup 1.0000x reference)
//
#include <hip/hip_runtime.h>
#include <cstdint>
#include <cstddef>

// ---------------- types ----------------
typedef _Float16 half8 __attribute__((ext_vector_type(8)));
typedef float floatx4 __attribute__((ext_vector_type(4)));

typedef __attribute__((address_space(3))) unsigned lds_u32;
typedef const __attribute__((address_space(1))) unsigned glb_u32;

__device__ __forceinline__ void glds16(const void* g, void* l) {
    // async global->LDS, 16B per lane; LDS dest = wave-uniform base + lane*16
    __builtin_amdgcn_global_load_lds((glb_u32*)g, (lds_u32*)l, 16, 0, 0);
}

template <int N>
__device__ __forceinline__ void waitv() {
    asm volatile("s_waitcnt vmcnt(%0)" :: "n"(N) : "memory");
}

__device__ __forceinline__ void bar() {
    asm volatile("" ::: "memory");
    __builtin_amdgcn_s_barrier();
    asm volatile("" ::: "memory");
}

__device__ __forceinline__ float fast_tanh(float x) {
    float ax = fabsf(x);
    float e  = __expf(-2.0f * ax);
    float t  = (1.0f - e) / (1.0f + e);
    return x < 0.0f ? -t : t;
}

// ---------------- XCD-aware block mapping ----------------
template <int MT, int NT, int NPX>
__device__ __forceinline__ void map_block(int id, int& mt, int& nt) {
    constexpr int NG  = NT / NPX;   // n-groups
    constexpr int XPG = 8 / NG;     // XCDs per group
    const int xcd  = id & 7;
    const int slot = id >> 3;
    nt = (xcd % NG) * NPX + (slot % NPX);
    mt = (xcd / NG) * (MT / XPG) + slot / NPX;
}

// ---------------- GEMM core: m201-style pipelined double buffer -----------
// C[TBM x TBN] = A[TBM x K] * BT[TBN x K]^T, both fp16 row-major (BT = B^T).
// NW waves, wave grid RW x CW, wave tile 64x64 (MF=NF=4): minimizes LDS
// fragment reads per MFMA (MF+NF per k-half).
//
// BK=64 double buffer; staging split into two k-half sub-stages of LPH glds
// per wave. Per K-step t (reads buf cur=t&1, stages t+1 into cur^1):
//   vmcnt(LPH)  barrier          <- T0(t) landed; T1(t) stays in flight
//   issue T0(t+1) (LPH glds)     <- overlaps with reads+MFMAs below
//   ds_read h0 frags (MF+NF b128) -> 16 MFMA (k-half 0)
//   vmcnt(LPH)  barrier          <- T1(t) landed; T0(t+1) stays in flight
//   issue T1(t+1)
//   ds_read h1 frags -> 16 MFMA (k-half 1)
//   lgkmcnt(0)                   <- buf reads retired before next bar
// vmcnt never drains to 0 in steady state (T4, m218: +38% vs drain-0);
// 2 barriers per 64-k step. setprio(1) around MFMA cluster (T5).
//
// LDS swizzle (verified conflict-free rounds 0-1, SQ_LDS_BANK_CONFLICT=0):
// per 16-row x 32-k chunk (512 elems), staging lane j writes 16B k-chunk
// kq=(j&3)^((j>>3)&3) of row j>>2; fragment read lane (quad,l16) reads unit
// l16*4 + (quad ^ ((l16>>1)&3)).
template <int TBM, int TBN, int MF, int NF, int NW>
__device__ __forceinline__ void gemm_acc_pipe(const _Float16* __restrict__ A,
                                              const _Float16* __restrict__ BT,
                                              size_t m0, size_t n0,
                                              int K, floatx4 acc[MF][NF]) {
    constexpr int CW = TBN / (16 * NF);   // waves along n
    constexpr int RW = TBM / (16 * MF);   // waves along m
    static_assert(RW * CW == NW, "wave grid must use all waves");
    constexpr int NCA = TBM / 16;         // A chunks per k-half
    constexpr int NCB = TBN / 16;         // B chunks per k-half
    static_assert(NCA % NW == 0 && NCB % NW == 0, "uniform per-wave staging");
    constexpr int APW = NCA / NW;
    constexpr int BPW = NCB / NW;
    constexpr int LPH = APW + BPW;        // glds per wave per k-half stage
    constexpr int AH  = TBM * 32;         // elems per k-half of A buffer
    constexpr int BH  = TBN * 32;

    __shared__ __align__(16) _Float16 As[2][TBM * 64];
    __shared__ __align__(16) _Float16 Bs[2][TBN * 64];

    const int tid  = threadIdx.x;
    const int lane = tid & 63;
    const int wid  = tid >> 6;

    const int srow = lane >> 2;                      // row within 16-row chunk
    const int skq  = (lane & 3) ^ ((lane >> 3) & 3); // swizzled 16B k-chunk
    const int quad = lane >> 4;
    const int l16  = lane & 15;
    const int wm   = (wid / CW) * (16 * MF);
    const int wn   = (wid % CW) * (16 * NF);
    const int rdoff = l16 * 32 + ((quad ^ ((l16 >> 1) & 3)) << 3);

#pragma unroll
    for (int i = 0; i < MF; ++i)
#pragma unroll
        for (int j = 0; j < NF; ++j)
            acc[i][j] = 0.0f;

    auto stageH = [&](int b, int p, int h) {
        const int kk = p * 64 + h * 32 + skq * 8;
#pragma unroll
        for (int c = 0; c < APW; ++c) {
            const int ch = wid + c * NW;
            glds16(A + (m0 + ch * 16 + srow) * (size_t)K + kk,
                   &As[b][h * AH + ch * 512]);
        }
#pragma unroll
        for (int c = 0; c < BPW; ++c) {
            const int ch = wid + c * NW;
            glds16(BT + (n0 + ch * 16 + srow) * (size_t)K + kk,
                   &Bs[b][h * BH + ch * 512]);
        }
    };

    auto halfc = [&](int b, int h) {
        half8 av[MF], bv[NF];
#pragma unroll
        for (int i = 0; i < MF; ++i)
            av[i] = *(const half8*)(&As[b][h * AH + ((wm >> 4) + i) * 512 + rdoff]);
#pragma unroll
        for (int j = 0; j < NF; ++j)
            bv[j] = *(const half8*)(&Bs[b][h * BH + ((wn >> 4) + j) * 512 + rdoff]);
        __builtin_amdgcn_s_setprio(1);
#pragma unroll
        for (int i = 0; i < MF; ++i)
#pragma unroll
            for (int j = 0; j < NF; ++j)
                acc[i][j] = __builtin_amdgcn_mfma_f32_16x16x32_f16(av[i], bv[j], acc[i][j], 0, 0, 0);
        __builtin_amdgcn_s_setprio(0);
    };

    stageH(0, 0, 0);
    stageH(0, 0, 1);

    const int NP = K / 64;
    for (int t = 0; t < NP; ++t) {
        const int cur = t & 1;
        const bool pf = (t + 1 < NP);    // wave-uniform

        waitv<LPH>();                    // T0(t) landed; newer stay in flight
        bar();                           // all waves' T0(t) landed; prev-step
                                         // reads retired -> cur^1 writable
        if (pf) stageH(cur ^ 1, t + 1, 0);
        halfc(cur, 0);

        if (pf) waitv<LPH>(); else waitv<0>();  // T1(t) landed
        bar();
        if (pf) stageH(cur ^ 1, t + 1, 1);
        halfc(cur, 1);

        asm volatile("s_waitcnt lgkmcnt(0)" ::: "memory");  // reads retired
    }
}

// C/D layout (verified m89/m91): col = lane&15, row = quad*4 + reg.

// ---------------- GEMM + bias (+ t*brow) + tanh -> fp16 out ----------------
// 256x128 tile, 512 threads (8 waves of 64x64), 96 KB LDS, 1 block/CU,
// 256 blocks (1/CU), XCD-mapped.
template <bool WITH_T, int MT, int NT>
__global__ __launch_bounds__(512, 2)
void gemm_bias_tanh(const _Float16* __restrict__ A, const _Float16* __restrict__ BT,
                    _Float16* __restrict__ out, const float* __restrict__ bias,
                    const float* __restrict__ brow, float t, int N, int K) {
    int mt, nt;
    map_block<MT, NT, 4>(blockIdx.x, mt, nt);
    const size_t bm0 = (size_t)mt * 256;
    const size_t bn0 = (size_t)nt * 128;

    floatx4 acc[4][4];
    gemm_acc_pipe<256, 128, 4, 4, 8>(A, BT, bm0, bn0, K, acc);

    const int tid  = threadIdx.x;
    const int lane = tid & 63;
    const int wid  = tid >> 6;          // 0..7; wave grid 4 (m) x 2 (n)
    const int quad = lane >> 4;
    const int l16  = lane & 15;
    const size_t m0 = bm0 + (size_t)(wid >> 1) * 64;
    const size_t n0 = bn0 + (size_t)(wid & 1) * 64;

#pragma unroll
    for (int j = 0; j < 4; ++j) {
        const size_t col = n0 + j * 16 + l16;
        float b = bias[col];
        if (WITH_T) b += t * brow[col];
#pragma unroll
        for (int i = 0; i < 4; ++i) {
            const size_t rbase = m0 + i * 16 + quad * 4;
#pragma unroll
            for (int r = 0; r < 4; ++r) {
                out[(rbase + r) * (size_t)N + col] = (_Float16)fast_tanh(acc[i][j][r] + b);
            }
        }
    }
}

// ---------------- GEMM3 (128x128 tile, 4 waves of 64x64) + RK4 stage -------
// 64 KB LDS -> 2 blocks/CU (TLP for the fp32 epilogue), 256 blocks.
__global__ __launch_bounds__(256, 2)
void gemm_k_stage(const _Float16* __restrict__ A, const _Float16* __restrict__ BT,
                  const float* __restrict__ bias, float* __restrict__ hstate,
                  float* __restrict__ accb, _Float16* __restrict__ x,
                  int stage, float c, float dt6, int N, int K) {
    int mt, nt;
    map_block<32, 8, 2>(blockIdx.x, mt, nt);
    const size_t bm0 = (size_t)mt * 128;
    const size_t bn0 = (size_t)nt * 128;

    floatx4 acc[4][4];
    gemm_acc_pipe<128, 128, 4, 4, 4>(A, BT, bm0, bn0, K, acc);

    const int tid  = threadIdx.x;
    const int lane = tid & 63;
    const int wid  = tid >> 6;          // 0..3; wave grid 2 (m) x 2 (n)
    const int quad = lane >> 4;
    const int l16  = lane & 15;
    const size_t m0 = bm0 + (size_t)(wid >> 1) * 64;
    const size_t n0 = bn0 + (size_t)(wid & 1) * 64;

#pragma unroll
    for (int j = 0; j < 4; ++j) {
        const size_t col = n0 + j * 16 + l16;
        const float b = bias[col];
#pragma unroll
        for (int i = 0; i < 4; ++i) {
            const size_t rbase = m0 + i * 16 + quad * 4;
#pragma unroll
            for (int r = 0; r < 4; ++r) {
                const size_t idx = (rbase + r) * (size_t)N + col;
                const float k = acc[i][j][r] + b;
                if (stage == 0) {
                    accb[idx] = k;
                    x[idx] = (_Float16)(hstate[idx] + c * k);
                } else if (stage < 3) {
                    accb[idx] += 2.0f * k;
                    x[idx] = (_Float16)(hstate[idx] + c * k);
                } else {
                    const float hn = hstate[idx] + dt6 * (accb[idx] + k);
                    hstate[idx] = hn;
                    x[idx] = (_Float16)hn;
                }
            }
        }
    }
}

// ---------------- setup kernels ----------------
__global__ __launch_bounds__(256)
void transposeW(const float* __restrict__ W, _Float16* __restrict__ WT,
                int K, int N) {
    __shared__ float tile[32][33];
    const int tx = threadIdx.x;          // 0..31
    const int ty = threadIdx.y;          // 0..7
    const int n0 = blockIdx.x * 32;
    const int k0 = blockIdx.y * 32;
#pragma unroll
    for (int r = ty; r < 32; r += 8)
        tile[r][tx] = W[(size_t)(k0 + r) * N + n0 + tx];
    __syncthreads();
#pragma unroll
    for (int r = ty; r < 32; r += 8)
        WT[(size_t)(n0 + r) * K + k0 + tx] = (_Float16)tile[tx][r];
}

__global__ void copy_row(const float* __restrict__ W1, float* __restrict__ w1row, int N) {
    const int n = blockIdx.x * 256 + threadIdx.x;
    if (n < N) w1row[n] = W1[(size_t)1024 * N + n];
}

__global__ void init_h(const float* __restrict__ h0, float* __restrict__ hstate,
                       _Float16* __restrict__ x, int n) {
    const int i = blockIdx.x * 256 + threadIdx.x;
    if (i < n) {
        const float v = h0[i];
        hstate[i] = v;
        x[i] = (_Float16)v;
    }
}

// ---------------- launch ----------------
extern "C" void kernel_launch(void* const* d_in, const int* in_sizes, int n_in,
                              void* d_out, int out_size, void* d_ws, size_t ws_size,
                              hipStream_t stream) {
    const int B = 4096, H = 1024, H2 = 2048;

    const float* h0 = (const float*)d_in[0];
    const float* W1 = (const float*)d_in[1];  // (1025, 2048)
    const float* b1 = (const float*)d_in[2];  // (2048,)
    const float* W2 = (const float*)d_in[3];  // (2048, 2048)
    const float* b2 = (const float*)d_in[4];  // (2048,)
    const float* W3 = (const float*)d_in[5];  // (2048, 1024)
    const float* b3 = (const float*)d_in[6];  // (1024,)

    float* hstate = (float*)d_out;            // B*H fp32 state, final answer

    char* ws = (char*)d_ws;
    _Float16* x    = (_Float16*)ws; ws += (size_t)B * H  * 2;  // GEMM1 input
    _Float16* a1   = (_Float16*)ws; ws += (size_t)B * H2 * 2;  // layer-1 act
    _Float16* a2   = (_Float16*)ws; ws += (size_t)B * H2 * 2;  // layer-2 act
    float*    accb = (float*)ws;    ws += (size_t)B * H  * 4;  // RK4 k-accum
    _Float16* W1T  = (_Float16*)ws; ws += (size_t)H2 * H  * 2; // (2048,1024)
    _Float16* W2T  = (_Float16*)ws; ws += (size_t)H2 * H2 * 2; // (2048,2048)
    _Float16* W3T  = (_Float16*)ws; ws += (size_t)H  * H2 * 2; // (1024,2048)
    float*   w1row = (float*)ws;    ws += (size_t)H2 * 4;      // t-row of W1, fp32

    // weight conversion + transpose (runs every call; weights restored by harness)
    const dim3 tblk(32, 8);
    transposeW<<<dim3(H2 / 32, H  / 32), tblk, 0, stream>>>(W1, W1T, H,  H2);
    transposeW<<<dim3(H2 / 32, H2 / 32), tblk, 0, stream>>>(W2, W2T, H2, H2);
    transposeW<<<dim3(H  / 32, H2 / 32), tblk, 0, stream>>>(W3, W3T, H2, H);
    copy_row<<<dim3(H2 / 256), 256, 0, stream>>>(W1, w1row, H2);
    init_h<<<dim3((B * H + 255) / 256), 256, 0, stream>>>(h0, hstate, x, B * H);

    const float dt  = 0.1f;
    const float dt2 = 0.05f;
    const float dt6 = dt / 6.0f;

    const dim3 blk12(512);
    const dim3 blk3(256);
    const int g12 = (B / 256) * (H2 / 128);   // 256 blocks, 1/CU, XCD-mapped
    const int g3  = (B / 128) * (H / 128);    // 256 blocks, 2/CU, XCD-mapped

    for (int s = 0; s < 10; ++s) {
        const float ti = (float)s * dt;

        // k1 = f(ti, h)
        gemm_bias_tanh<true , 16, 16><<<g12, blk12, 0, stream>>>(x,  W1T, a1, b1, w1row, ti,       H2, H);
        gemm_bias_tanh<false, 16, 16><<<g12, blk12, 0, stream>>>(a1, W2T, a2, b2, nullptr, 0.f,    H2, H2);
        gemm_k_stage<<<g3, blk3, 0, stream>>>(a2, W3T, b3, hstate, accb, x, 0, dt2, dt6, H, H2);

        // k2 = f(ti+dt/2, h + dt/2*k1)
        gemm_bias_tanh<true , 16, 16><<<g12, blk12, 0, stream>>>(x,  W1T, a1, b1, w1row, ti + dt2, H2, H);
        gemm_bias_tanh<false, 16, 16><<<g12, blk12, 0, stream>>>(a1, W2T, a2, b2, nullptr, 0.f,    H2, H2);
        gemm_k_stage<<<g3, blk3, 0, stream>>>(a2, W3T, b3, hstate, accb, x, 1, dt2, dt6, H, H2);

        // k3 = f(ti+dt/2, h + dt/2*k2)
        gemm_bias_tanh<true , 16, 16><<<g12, blk12, 0, stream>>>(x,  W1T, a1, b1, w1row, ti + dt2, H2, H);
        gemm_bias_tanh<false, 16, 16><<<g12, blk12, 0, stream>>>(a1, W2T, a2, b2, nullptr, 0.f,    H2, H2);
        gemm_k_stage<<<g3, blk3, 0, stream>>>(a2, W3T, b3, hstate, accb, x, 2, dt,  dt6, H, H2);

        // k4 = f(ti+dt, h + dt*k3); h += dt/6*(k1+2k2+2k3+k4)
        gemm_bias_tanh<true , 16, 16><<<g12, blk12, 0, stream>>>(x,  W1T, a1, b1, w1row, ti + dt,  H2, H);
        gemm_bias_tanh<false, 16, 16><<<g12, blk12, 0, stream>>>(a1, W2T, a2, b2, nullptr, 0.f,    H2, H2);
        gemm_k_stage<<<g3, blk3, 0, stream>>>(a2, W3T, b3, hstate, accb, x, 3, dt,  dt6, H, H2);
    }
}

// Round 3
// 4685.431 us; speedup vs baseline: 1.3516x; 1.3516x over previous
//
#include <hip/hip_runtime.h>
#include <cstdint>
#include <cstddef>

// ---------------- types ----------------
typedef _Float16 half8 __attribute__((ext_vector_type(8)));
typedef float floatx4 __attribute__((ext_vector_type(4)));

typedef __attribute__((address_space(3))) unsigned lds_u32;
typedef const __attribute__((address_space(1))) unsigned glb_u32;

#define BK 64   // two 32-k sub-tiles per LDS buffer; halves barrier-drain count

__device__ __forceinline__ void glds16(const void* g, void* l) {
    // async global->LDS, 16B per lane; LDS dest = wave-uniform base + lane*16
    __builtin_amdgcn_global_load_lds((glb_u32*)g, (lds_u32*)l, 16, 0, 0);
}

__device__ __forceinline__ float fast_tanh(float x) {
    float ax = fabsf(x);
    float e  = __expf(-2.0f * ax);
    float t  = (1.0f - e) / (1.0f + e);
    return x < 0.0f ? -t : t;
}

// ---------------- XCD-aware block mapping ----------------
template <int MT, int NT, int NPX>
__device__ __forceinline__ void map_block(int id, int& mt, int& nt) {
    constexpr int NG  = NT / NPX;   // n-groups
    constexpr int XPG = 8 / NG;     // XCDs per group
    const int xcd  = id & 7;
    const int slot = id >> 3;
    nt = (xcd % NG) * NPX + (slot % NPX);
    mt = (xcd / NG) * (MT / XPG) + slot / NPX;
}

// ---------------- GEMM core (round-0 verbatim): double-buffered -----------
// C[TBM x TBN] = A[TBM x K] * BT[TBN x K]^T, both fp16 row-major (BT = B^T).
// Per 16-row x 32-k chunk (512 elems): staging lane j (row j>>2) fetches
// 16B k-chunk kq = (j&3) ^ ((j>>3)&3) of the row's 64B -> LDS unit j.
// Fragment read: lane (quad,l16) reads unit l16*4 + (quad ^ ((l16>>1)&3)):
// conflict-free (verified: SQ_LDS_BANK_CONFLICT = 0).
template <int TBM, int TBN, int MF, int NF, int NW>
__device__ __forceinline__ void gemm_acc_db(const _Float16* __restrict__ A,
                                            const _Float16* __restrict__ BT,
                                            size_t m0, size_t n0,
                                            int K, floatx4 acc[MF][NF]) {
    constexpr int CW = TBN / (16 * NF);   // waves along n
    constexpr int RW = TBM / (16 * MF);   // waves along m
    static_assert(RW * CW == NW, "wave grid must use all waves");
    constexpr int AH = TBM * 32;          // elems per 32-k half of A tile
    constexpr int BH = TBN * 32;

    __shared__ __align__(16) _Float16 As[2][TBM * BK];
    __shared__ __align__(16) _Float16 Bs[2][TBN * BK];

    const int tid  = threadIdx.x;
    const int lane = tid & 63;
    const int wid  = tid >> 6;

    const int srow = lane >> 2;                     // row within 16-row chunk
    const int skq  = (lane & 3) ^ ((lane >> 3) & 3);// swizzled 16B k-chunk
    const int quad = lane >> 4;
    const int l16  = lane & 15;
    const int wm   = (wid / CW) * (16 * MF);
    const int wn   = (wid % CW) * (16 * NF);

#pragma unroll
    for (int i = 0; i < MF; ++i)
#pragma unroll
        for (int j = 0; j < NF; ++j)
            acc[i][j] = 0.0f;

    auto stage = [&](int buf, int k0) {
#pragma unroll
        for (int h = 0; h < 2; ++h) {
#pragma unroll
            for (int c = wid; c < TBM / 16; c += NW)
                glds16(A + (m0 + c * 16 + srow) * (size_t)K + k0 + h * 32 + skq * 8,
                       &As[buf][h * AH + c * 512]);
#pragma unroll
            for (int c = wid; c < TBN / 16; c += NW)
                glds16(BT + (n0 + c * 16 + srow) * (size_t)K + k0 + h * 32 + skq * 8,
                       &Bs[buf][h * BH + c * 512]);
        }
    };

    const int rdoff = l16 * 32 + ((quad ^ ((l16 >> 1) & 3)) << 3);

    stage(0, 0);
    int cur = 0;
    for (int k0 = 0; k0 < K; k0 += BK) {
        __syncthreads();                           // buf[cur] ready (vmcnt drain)
        if (k0 + BK < K) stage(cur ^ 1, k0 + BK);  // overlap with MFMAs below

#pragma unroll
        for (int h = 0; h < 2; ++h) {
            half8 av[MF], bv[NF];
#pragma unroll
            for (int i = 0; i < MF; ++i)
                av[i] = *(const half8*)(&As[cur][h * AH + ((wm >> 4) + i) * 512 + rdoff]);
#pragma unroll
            for (int j = 0; j < NF; ++j)
                bv[j] = *(const half8*)(&Bs[cur][h * BH + ((wn >> 4) + j) * 512 + rdoff]);
#pragma unroll
            for (int i = 0; i < MF; ++i)
#pragma unroll
                for (int j = 0; j < NF; ++j)
                    acc[i][j] = __builtin_amdgcn_mfma_f32_16x16x32_f16(av[i], bv[j], acc[i][j], 0, 0, 0);
        }
        cur ^= 1;
    }
}

// C/D layout (verified m89/m91): col = lane&15, row = quad*4 + reg.

// ---------------- GEMM1: round-0 kernel (128x128, 8 waves of 64x32) -------
template <bool WITH_T, int MT, int NT>
__global__ __launch_bounds__(512)
void gemm_bias_tanh(const _Float16* __restrict__ A, const _Float16* __restrict__ BT,
                    _Float16* __restrict__ out, const float* __restrict__ bias,
                    const float* __restrict__ brow, float t, int N, int K) {
    int mt, nt;
    map_block<MT, NT, 4>(blockIdx.x, mt, nt);
    const size_t bm0 = (size_t)mt * 128;
    const size_t bn0 = (size_t)nt * 128;

    floatx4 acc[4][2];
    gemm_acc_db<128, 128, 4, 2, 8>(A, BT, bm0, bn0, K, acc);

    const int tid  = threadIdx.x;
    const int lane = tid & 63;
    const int wid  = tid >> 6;          // 0..7; wave grid 2 (m) x 4 (n)
    const int quad = lane >> 4;
    const int l16  = lane & 15;
    const size_t m0 = bm0 + (size_t)(wid / 4) * 64;
    const size_t n0 = bn0 + (size_t)(wid % 4) * 32;

#pragma unroll
    for (int j = 0; j < 2; ++j) {
        const size_t col = n0 + j * 16 + l16;
        float b = bias[col];
        if (WITH_T) b += t * brow[col];
#pragma unroll
        for (int i = 0; i < 4; ++i) {
            const size_t rbase = m0 + i * 16 + quad * 4;
#pragma unroll
            for (int r = 0; r < 4; ++r) {
                out[(rbase + r) * (size_t)N + col] = (_Float16)fast_tanh(acc[i][j][r] + b);
            }
        }
    }
}

// ---------------- GEMM2 experiment: 256x128 tile, 8 waves of 64x64 --------
// Same skeleton as gemm_acc_db (one __syncthreads per 64-k, stage-all right
// after, dbuf) but: wave tile 64x64 (LDS reads/MFMA 0.75KB->0.5KB, ceiling
// 42%->62%), B k-half fragments held in VGPRs across the 4 row phases,
// setprio(1) around each 8-MFMA cluster (T5). 96KB LDS -> 1 block/CU.
__global__ __launch_bounds__(512, 2)
void gemm_tanh2(const _Float16* __restrict__ A, const _Float16* __restrict__ BT,
                _Float16* __restrict__ out, const float* __restrict__ bias,
                int N, int K) {
    int mt, nt;
    map_block<16, 16, 4>(blockIdx.x, mt, nt);
    const size_t bm0 = (size_t)mt * 256;
    const size_t bn0 = (size_t)nt * 128;

    constexpr int AH = 256 * 32;   // elems per 32-k half of A buffer
    constexpr int BH = 128 * 32;

    __shared__ __align__(16) _Float16 As[2][256 * 64];   // 64 KB
    __shared__ __align__(16) _Float16 Bs[2][128 * 64];   // 32 KB

    const int tid  = threadIdx.x;
    const int lane = tid & 63;
    const int wid  = tid >> 6;          // 0..7; wave grid 4 (m) x 2 (n)
    const int srow = lane >> 2;
    const int skq  = (lane & 3) ^ ((lane >> 3) & 3);
    const int quad = lane >> 4;
    const int l16  = lane & 15;
    const int wmc  = (wid >> 1) * 4;    // A row-chunk base (wave row / 16)
    const int wnc  = (wid & 1) * 4;     // B col-chunk base
    const int rdoff = l16 * 32 + ((quad ^ ((l16 >> 1) & 3)) << 3);

    floatx4 acc[4][4];
#pragma unroll
    for (int i = 0; i < 4; ++i)
#pragma unroll
        for (int j = 0; j < 4; ++j)
            acc[i][j] = 0.0f;

    // 48 staging chunks (A: 32 = 16 rows x 2 kh, B: 16), 6 glds per wave.
    auto stage_all = [&](int b, int k0) {
        const int kk = k0 + skq * 8;
#pragma unroll
        for (int u = 0; u < 4; ++u) {
            const int c  = wid + u * 8;      // 0..31
            const int ra = c >> 1, kh = c & 1;
            glds16(A + (bm0 + ra * 16 + srow) * (size_t)K + kk + kh * 32,
                   &As[b][kh * AH + ra * 512]);
        }
#pragma unroll
        for (int u = 0; u < 2; ++u) {
            const int c  = wid + u * 8;      // 0..15
            const int rb = c >> 1, kh = c & 1;
            glds16(BT + (bn0 + rb * 16 + srow) * (size_t)K + kk + kh * 32,
                   &Bs[b][kh * BH + rb * 512]);
        }
    };

    stage_all(0, 0);
    const int NP = K / 64;
    int cur = 0;
    for (int t = 0; t < NP; ++t) {
        __syncthreads();                       // buf[cur] ready (vmcnt drain)
        if (t + 1 < NP) stage_all(cur ^ 1, (t + 1) * 64);

        half8 bv[2][4];                        // B k-halves live across phases
#pragma unroll
        for (int h = 0; h < 2; ++h)
#pragma unroll
            for (int j = 0; j < 4; ++j)
                bv[h][j] = *(const half8*)(&Bs[cur][h * BH + (wnc + j) * 512 + rdoff]);

#pragma unroll
        for (int i = 0; i < 4; ++i) {          // row phases: 2 reads + 8 MFMA
            half8 a0 = *(const half8*)(&As[cur][0 * AH + (wmc + i) * 512 + rdoff]);
            half8 a1 = *(const half8*)(&As[cur][1 * AH + (wmc + i) * 512 + rdoff]);
            __builtin_amdgcn_s_setprio(1);
#pragma unroll
            for (int j = 0; j < 4; ++j)
                acc[i][j] = __builtin_amdgcn_mfma_f32_16x16x32_f16(a0, bv[0][j], acc[i][j], 0, 0, 0);
#pragma unroll
            for (int j = 0; j < 4; ++j)
                acc[i][j] = __builtin_amdgcn_mfma_f32_16x16x32_f16(a1, bv[1][j], acc[i][j], 0, 0, 0);
            __builtin_amdgcn_s_setprio(0);
        }
        cur ^= 1;
    }

    const size_t m0 = bm0 + (size_t)(wid >> 1) * 64;
    const size_t n0 = bn0 + (size_t)(wid & 1) * 64;
#pragma unroll
    for (int j = 0; j < 4; ++j) {
        const size_t col = n0 + j * 16 + l16;
        const float b = bias[col];
#pragma unroll
        for (int i = 0; i < 4; ++i) {
            const size_t rbase = m0 + i * 16 + quad * 4;
#pragma unroll
            for (int r = 0; r < 4; ++r) {
                out[(rbase + r) * (size_t)N + col] = (_Float16)fast_tanh(acc[i][j][r] + b);
            }
        }
    }
}

// ---------------- GEMM3 (round-0 verbatim): 64x128 tile + RK4 stage -------
__global__ __launch_bounds__(512)
void gemm_k_stage(const _Float16* __restrict__ A, const _Float16* __restrict__ BT,
                  const float* __restrict__ bias, float* __restrict__ hstate,
                  float* __restrict__ accb, _Float16* __restrict__ x,
                  int stage, float c, float dt6, int N, int K) {
    int mt, nt;
    map_block<64, 8, 2>(blockIdx.x, mt, nt);
    const size_t bm0 = (size_t)mt * 64;
    const size_t bn0 = (size_t)nt * 128;

    floatx4 acc[2][2];
    gemm_acc_db<64, 128, 2, 2, 8>(A, BT, bm0, bn0, K, acc);

    const int tid  = threadIdx.x;
    const int lane = tid & 63;
    const int wid  = tid >> 6;          // wave grid 2 (m) x 4 (n)
    const int quad = lane >> 4;
    const int l16  = lane & 15;
    const size_t m0 = bm0 + (size_t)(wid / 4) * 32;
    const size_t n0 = bn0 + (size_t)(wid % 4) * 32;

#pragma unroll
    for (int j = 0; j < 2; ++j) {
        const size_t col = n0 + j * 16 + l16;
        const float b = bias[col];
#pragma unroll
        for (int i = 0; i < 2; ++i) {
            const size_t rbase = m0 + i * 16 + quad * 4;
#pragma unroll
            for (int r = 0; r < 4; ++r) {
                const size_t idx = (rbase + r) * (size_t)N + col;
                const float k = acc[i][j][r] + b;
                if (stage == 0) {
                    accb[idx] = k;
                    x[idx] = (_Float16)(hstate[idx] + c * k);
                } else if (stage < 3) {
                    accb[idx] += 2.0f * k;
                    x[idx] = (_Float16)(hstate[idx] + c * k);
                } else {
                    const float hn = hstate[idx] + dt6 * (accb[idx] + k);
                    hstate[idx] = hn;
                    x[idx] = (_Float16)hn;
                }
            }
        }
    }
}

// ---------------- setup kernels ----------------
__global__ __launch_bounds__(256)
void transposeW(const float* __restrict__ W, _Float16* __restrict__ WT,
                int K, int N) {
    __shared__ float tile[32][33];
    const int tx = threadIdx.x;          // 0..31
    const int ty = threadIdx.y;          // 0..7
    const int n0 = blockIdx.x * 32;
    const int k0 = blockIdx.y * 32;
#pragma unroll
    for (int r = ty; r < 32; r += 8)
        tile[r][tx] = W[(size_t)(k0 + r) * N + n0 + tx];
    __syncthreads();
#pragma unroll
    for (int r = ty; r < 32; r += 8)
        WT[(size_t)(n0 + r) * K + k0 + tx] = (_Float16)tile[tx][r];
}

__global__ void copy_row(const float* __restrict__ W1, float* __restrict__ w1row, int N) {
    const int n = blockIdx.x * 256 + threadIdx.x;
    if (n < N) w1row[n] = W1[(size_t)1024 * N + n];
}

__global__ void init_h(const float* __restrict__ h0, float* __restrict__ hstate,
                       _Float16* __restrict__ x, int n) {
    const int i = blockIdx.x * 256 + threadIdx.x;
    if (i < n) {
        const float v = h0[i];
        hstate[i] = v;
        x[i] = (_Float16)v;
    }
}

// ---------------- launch ----------------
extern "C" void kernel_launch(void* const* d_in, const int* in_sizes, int n_in,
                              void* d_out, int out_size, void* d_ws, size_t ws_size,
                              hipStream_t stream) {
    const int B = 4096, H = 1024, H2 = 2048;

    const float* h0 = (const float*)d_in[0];
    const float* W1 = (const float*)d_in[1];  // (1025, 2048)
    const float* b1 = (const float*)d_in[2];  // (2048,)
    const float* b2 = (const float*)d_in[4];  // (2048,)
    const float* W2 = (const float*)d_in[3];  // (2048, 2048)
    const float* W3 = (const float*)d_in[5];  // (2048, 1024)
    const float* b3 = (const float*)d_in[6];  // (1024,)

    float* hstate = (float*)d_out;            // B*H fp32 state, final answer

    char* ws = (char*)d_ws;
    _Float16* x    = (_Float16*)ws; ws += (size_t)B * H  * 2;  // GEMM1 input
    _Float16* a1   = (_Float16*)ws; ws += (size_t)B * H2 * 2;  // layer-1 act
    _Float16* a2   = (_Float16*)ws; ws += (size_t)B * H2 * 2;  // layer-2 act
    float*    accb = (float*)ws;    ws += (size_t)B * H  * 4;  // RK4 k-accum
    _Float16* W1T  = (_Float16*)ws; ws += (size_t)H2 * H  * 2; // (2048,1024)
    _Float16* W2T  = (_Float16*)ws; ws += (size_t)H2 * H2 * 2; // (2048,2048)
    _Float16* W3T  = (_Float16*)ws; ws += (size_t)H  * H2 * 2; // (1024,2048)
    float*   w1row = (float*)ws;    ws += (size_t)H2 * 4;      // t-row of W1, fp32

    // weight conversion + transpose (runs every call; weights restored by harness)
    const dim3 tblk(32, 8);
    transposeW<<<dim3(H2 / 32, H  / 32), tblk, 0, stream>>>(W1, W1T, H,  H2);
    transposeW<<<dim3(H2 / 32, H2 / 32), tblk, 0, stream>>>(W2, W2T, H2, H2);
    transposeW<<<dim3(H  / 32, H2 / 32), tblk, 0, stream>>>(W3, W3T, H2, H);
    copy_row<<<dim3(H2 / 256), 256, 0, stream>>>(W1, w1row, H2);
    init_h<<<dim3((B * H + 255) / 256), 256, 0, stream>>>(h0, hstate, x, B * H);

    const float dt  = 0.1f;
    const float dt2 = 0.05f;
    const float dt6 = dt / 6.0f;

    const dim3 blk(512);
    const int g1 = (B / 128) * (H2 / 128);    // 512 blocks (round-0)
    const int g2 = (B / 256) * (H2 / 128);    // 256 blocks (new core)
    const int g3 = (B / 64) * (H / 128);      // 512 blocks (round-0)

    for (int s = 0; s < 10; ++s) {
        const float ti = (float)s * dt;

        // k1 = f(ti, h)
        gemm_bias_tanh<true , 32, 16><<<g1, blk, 0, stream>>>(x,  W1T, a1, b1, w1row, ti,       H2, H);
        gemm_tanh2<<<g2, blk, 0, stream>>>(a1, W2T, a2, b2, H2, H2);
        gemm_k_stage<<<g3, blk, 0, stream>>>(a2, W3T, b3, hstate, accb, x, 0, dt2, dt6, H, H2);

        // k2 = f(ti+dt/2, h + dt/2*k1)
        gemm_bias_tanh<true , 32, 16><<<g1, blk, 0, stream>>>(x,  W1T, a1, b1, w1row, ti + dt2, H2, H);
        gemm_tanh2<<<g2, blk, 0, stream>>>(a1, W2T, a2, b2, H2, H2);
        gemm_k_stage<<<g3, blk, 0, stream>>>(a2, W3T, b3, hstate, accb, x, 1, dt2, dt6, H, H2);

        // k3 = f(ti+dt/2, h + dt/2*k2)
        gemm_bias_tanh<true , 32, 16><<<g1, blk, 0, stream>>>(x,  W1T, a1, b1, w1row, ti + dt2, H2, H);
        gemm_tanh2<<<g2, blk, 0, stream>>>(a1, W2T, a2, b2, H2, H2);
        gemm_k_stage<<<g3, blk, 0, stream>>>(a2, W3T, b3, hstate, accb, x, 2, dt,  dt6, H, H2);

        // k4 = f(ti+dt, h + dt*k3); h += dt/6*(k1+2k2+2k3+k4)
        gemm_bias_tanh<true , 32, 16><<<g1, blk, 0, stream>>>(x,  W1T, a1, b1, w1row, ti + dt,  H2, H);
        gemm_tanh2<<<g2, blk, 0, stream>>>(a1, W2T, a2, b2, H2, H2);
        gemm_k_stage<<<g3, blk, 0, stream>>>(a2, W3T, b3, hstate, accb, x, 3, dt,  dt6, H, H2);
    }
}